// Round 9
// baseline (13738.499 us; speedup 1.0000x reference)
//
#include <hip/hip_runtime.h>
#include <hip/hip_bf16.h>
#include <hip/hip_fp16.h>

// ---------------------------------------------------------------------------
// LSTMTagger: char-LSTM (4096x16, H=128) -> word-LSTM (serial 4096, H=512)
//             -> linear(64) + log_softmax.
// Wire dtype of float tensors detected at runtime (bf16 vs f32); kernels
// dual-path on device flag ws[0]: 1 = bf16, 0 = f32.
//
// Word LSTM (round 11): latency-targeted edition.
//   R8 established: step time (2.28us) is INVARIANT to compute/payload/
//   weight-traffic changes -> critical path = communication. Model:
//   poll-round = IC load latency ~900cy (vmcnt(0) per round), detect ~1.5
//   rounds ~560ns; store+IC ~200ns; post-detect compute ~600ns (incl. 64-lane
//   redundant quarter-rate transcendentals); + max-over-16-WG jitter.
//   (Also: SQ_LDS_BANK_CONFLICT == exactly #ds_read_b128 in R7 AND R8 ->
//   per-instruction artifact, not real conflicts. Dropped that thread.)
//   This round:
//   - PIPELINED POLL: 3 x 4-load rounds in flight, check the oldest;
//     compiler emits counted vmcnt -> round period ~latency/3. Plain HIP.
//   - gate math (5 exp + 5 rcp, quarter-rate) predicated to lanes 0/32
//     (the only lanes whose c,h are consumed) -> cuts transcendental issue.
//   - PINU4 pin removed (R8 proved it a no-op; VGPR stayed 32).
//   Protocol unchanged: 16 WGs x 16 waves, f16 line payload, 0xFFFFFFFF
//   sentinel, ONE 64B line store per WG, hout[2] double buffer, one barrier.
// ---------------------------------------------------------------------------

#define OFF_FLAG  0
#define OFF_CEMB  16
#define OFF_CWIH  8208
#define OFF_CBIH  40976
#define OFF_CBHH  41488
#define OFF_CWHH  42000
#define OFF_BIH   107536
#define OFF_BHH   109584
#define OFF_W1T   111632
#define OFF_CGE   144400
#define OFF_CH    209936
#define OFF_XP2   734224
#define OFF_HH    4928528
#define OFF_WHH16 5977104   /* word Whh as packed f16: 1048576 ushort = 2MB */

#define SENT 0xFFFFFFFFu

#ifndef __has_builtin
#define __has_builtin(x) 0
#endif
#if __has_builtin(__builtin_amdgcn_fdot2)
#define HASDOT2 1
#endif

typedef _Float16 v2h __attribute__((ext_vector_type(2)));

__device__ __forceinline__ float sigf(float x) { return 1.0f / (1.0f + __expf(-x)); }
__device__ __forceinline__ float tanh_f(float x) { return 2.0f * sigf(2.0f * x) - 1.0f; }
__device__ __forceinline__ float b2f_lo(unsigned u) { return __uint_as_float(u << 16); }
__device__ __forceinline__ float b2f_hi(unsigned u) { return __uint_as_float(u & 0xFFFF0000u); }
// f16 bits -> f32 via _Float16 (no header intrinsics needed)
__device__ __forceinline__ float h2f_lo(unsigned u) {
    union { unsigned short s; _Float16 h; } c;
    c.s = (unsigned short)(u & 0xFFFFu);
    return (float)c.h;
}
__device__ __forceinline__ float h2f_hi(unsigned u) {
    union { unsigned short s; _Float16 h; } c;
    c.s = (unsigned short)(u >> 16);
    return (float)c.h;
}
// f32 -> f16 bits (RNE via compiler _Float16 conversion)
__device__ __forceinline__ unsigned short f2h_bits(float f) {
    union { unsigned short s; _Float16 h; } c;
    c.h = (_Float16)f;
    return c.s;
}
// packed-f16 2-way dot: acc += w.lo*h.lo + w.hi*h.hi
__device__ __forceinline__ float dot2h(unsigned w, unsigned h, float acc) {
#ifdef HASDOT2
    union U { unsigned u; v2h v; };
    U uw; uw.u = w;
    U uh; uh.u = h;
    return __builtin_amdgcn_fdot2(uw.v, uh.v, acc, false);
#else
    return acc + h2f_lo(w) * h2f_lo(h) + h2f_hi(w) * h2f_hi(h);
#endif
}

// ---- D0: dtype detect. ---------------------------------------------------
__global__ void detect_kernel(const unsigned* __restrict__ w, int* __restrict__ flagp) {
    unsigned v = w[threadIdx.x];
    unsigned e = (v >> 7) & 0xFF;
    int inr = (e >= 100 && e <= 140) ? 1 : 0;
    unsigned long long m = __ballot(inr);
    if (threadIdx.x == 0) flagp[0] = (__popcll(m) >= 56) ? 1 : 0;
}

// ---- K0: (bf16|f32) -> f32 convert ---------------------------------------
__global__ void convf_kernel(const void* __restrict__ s, float* __restrict__ d,
                             int n, const int* __restrict__ flagp) {
    int i = blockIdx.x * 256 + threadIdx.x;
    if (i >= n) return;
    d[i] = flagp[0] ? __bfloat162float(((const __hip_bfloat16*)s)[i])
                    : ((const float*)s)[i];
}

// ---- K0b: W1 (64x512) -> W1T (512x64) f32 --------------------------------
__global__ void w1t_kernel(const void* __restrict__ W1, float* __restrict__ W1T,
                           const int* __restrict__ flagp) {
    int i = blockIdx.x * 256 + threadIdx.x;   // 0..32767
    int j = i & 63, k = i >> 6;
    W1T[i] = flagp[0] ? __bfloat162float(((const __hip_bfloat16*)W1)[j * 512 + k])
                      : ((const float*)W1)[j * 512 + k];
}

// ---- K0c: word Whh -> packed f16 -----------------------------------------
__global__ void whh16_kernel(const void* __restrict__ src, unsigned short* __restrict__ dst,
                             const int* __restrict__ flagp) {
    int i = blockIdx.x * 256 + threadIdx.x;   // 0..1048575
    float f = flagp[0] ? __bfloat162float(((const __hip_bfloat16*)src)[i])
                       : ((const float*)src)[i];
    dst[i] = f2h_bits(f);
}

// ---- K1: char gate table ------------------------------------------------
__global__ void __launch_bounds__(256) cge_kernel(
    const float* __restrict__ cemb, const float* __restrict__ cWih,
    const float* __restrict__ cbih, const float* __restrict__ cbhh,
    float* __restrict__ cge)
{
    __shared__ float xe[64];
    int c = blockIdx.x, tid = threadIdx.x;
    if (tid < 64) xe[tid] = cemb[c * 64 + tid];
    __syncthreads();
#pragma unroll
    for (int rep = 0; rep < 2; ++rep) {
        int j = rep * 256 + tid;
        float acc = cbih[j] + cbhh[j];
#pragma unroll 8
        for (int k = 0; k < 64; ++k)
            acc += xe[k] * cWih[j * 64 + k];
        cge[c * 512 + j] = acc;
    }
}

// ---- K2: char LSTM -------------------------------------------------------
__global__ void __launch_bounds__(256) char_lstm_kernel(
    const float* __restrict__ cge, const float* __restrict__ Whh,
    const int* __restrict__ chars, const int* __restrict__ lens,
    float* __restrict__ char_h)
{
    __shared__ float hls[16][128];
    int tid = threadIdx.x;
    int wl = tid >> 4, sl = tid & 15;
    int w = blockIdx.x * 16 + wl;
    int len = lens[w];
    const int* cw = chars + w * 16;
    float c[8];
#pragma unroll
    for (int q = 0; q < 8; ++q) { c[q] = 0.0f; hls[wl][sl * 8 + q] = 0.0f; }

    for (int t = 0; t < 16; ++t) {
        __syncthreads();
        int ch = cw[t];
        const float* xg = cge + ch * 512;
        float acc[4][8];
#pragma unroll
        for (int g = 0; g < 4; ++g)
#pragma unroll
            for (int q = 0; q < 8; ++q)
                acc[g][q] = xg[g * 128 + sl * 8 + q];

        const float4* h4 = (const float4*)hls[wl];
#pragma unroll
        for (int g = 0; g < 4; ++g) {
            const float4* wbase = ((const float4*)Whh) + (g * 128 + sl * 8) * 32;
            for (int k4 = 0; k4 < 32; ++k4) {
                float4 hv = h4[k4];
#pragma unroll
                for (int q = 0; q < 8; ++q) {
                    float4 wv = wbase[q * 32 + k4];
                    acc[g][q] += wv.x * hv.x + wv.y * hv.y + wv.z * hv.z + wv.w * hv.w;
                }
            }
        }
        __syncthreads();
        if (t < len) {
#pragma unroll
            for (int q = 0; q < 8; ++q) {
                float iv = sigf(acc[0][q]);
                float fv = sigf(acc[1][q]);
                float gv = tanh_f(acc[2][q]);
                float ov = sigf(acc[3][q]);
                c[q] = fv * c[q] + iv * gv;
                hls[wl][sl * 8 + q] = ov * tanh_f(c[q]);
            }
        }
    }
    __syncthreads();
#pragma unroll
    for (int q = 0; q < 8; ++q)
        char_h[w * 128 + sl * 8 + q] = hls[wl][sl * 8 + q];
}

// ---- K3: word x-part gates (bf16 out) ------------------------------------
__global__ void __launch_bounds__(256) xp2_kernel(
    const void* __restrict__ wemb, const int* __restrict__ x,
    const float* __restrict__ char_h, const void* __restrict__ Wraw,
    const float* __restrict__ bih, const float* __restrict__ bhh,
    __hip_bfloat16* __restrict__ xp2, const int* __restrict__ flagp)
{
    __shared__ float feat[16][384];
    int flag = flagp[0];
    int tid = threadIdx.x, tl = tid >> 4, sl = tid & 15;
    int t = blockIdx.x * 16 + tl;
    int xw = x[t];
    for (int idx = sl; idx < 384; idx += 16) {
        float v;
        if (idx < 256)
            v = flag ? __bfloat162float(((const __hip_bfloat16*)wemb)[(size_t)xw * 256 + idx])
                     : ((const float*)wemb)[(size_t)xw * 256 + idx];
        else
            v = char_h[t * 128 + (idx - 256)];
        feat[tl][idx] = v;
    }
    __syncthreads();

    const float4* f4 = (const float4*)feat[tl];
    for (int rb = 0; rb < 4; ++rb) {
        int r0 = rb * 512 + sl * 32;
        for (int qc = 0; qc < 4; ++qc) {
            int rr = r0 + qc * 8;
            float acc[8];
#pragma unroll
            for (int q = 0; q < 8; ++q)
                acc[q] = bih[rr + q] + bhh[rr + q];
            if (!flag) {
                const float4* wb = ((const float4*)Wraw) + (size_t)rr * 96;
                for (int k4 = 0; k4 < 96; ++k4) {
                    float4 fv = f4[k4];
#pragma unroll
                    for (int q = 0; q < 8; ++q) {
                        float4 wv = wb[q * 96 + k4];
                        acc[q] += wv.x * fv.x + wv.y * fv.y + wv.z * fv.z + wv.w * fv.w;
                    }
                }
            } else {
                const uint2* wb = ((const uint2*)Wraw) + (size_t)rr * 96;
                for (int k4 = 0; k4 < 96; ++k4) {
                    float4 fv = f4[k4];
#pragma unroll
                    for (int q = 0; q < 8; ++q) {
                        uint2 wv = wb[q * 96 + k4];
                        acc[q] += b2f_lo(wv.x) * fv.x + b2f_hi(wv.x) * fv.y
                                + b2f_lo(wv.y) * fv.z + b2f_hi(wv.y) * fv.w;
                    }
                }
            }
#pragma unroll
            for (int q = 0; q < 8; ++q)
                xp2[(size_t)t * 2048 + rr + q] = __float2bfloat16(acc[q]);
        }
    }
}

// ---- K5: serial word LSTM (16 WGs, f16 payload, pipelined poll) ----------
__global__ void __launch_bounds__(1024, 1) word_lstm_kernel(
    const __hip_bfloat16* __restrict__ xp2, const unsigned* __restrict__ whh16,
    unsigned* __restrict__ hview)
{
    __shared__ __align__(16) unsigned hbufA[16][160];
    __shared__ __align__(16) unsigned hbufB[16][160];
    __shared__ float hout[2][32];    // double-buffered fresh h (f32)
    int wg = blockIdx.x;
    int tid = threadIdx.x;
    int wave = tid >> 6, lane = tid & 63;
    int sp = lane >> 5;              // sub-slot 0/1 within the wave
    int g  = (lane >> 3) & 3;        // gate i/f/g/o
    int kk = lane & 7;               // k-chunk (64 h-values wide)
    int slot = wg * 32 + wave * 2 + sp;
    int grow = g * 512 + slot;

    // weights: Whh[grow][kk*64 .. +63] as 32 packed-f16 dwords = 8 uint4.
    // No pin: R8 proved pinning is a no-op; reloads (if any) hide under spin.
    const uint4* wr = (const uint4*)(whh16 + (size_t)grow * 256) + kk * 8;
    uint4 wa0 = wr[0], wa1 = wr[1], wa2 = wr[2], wa3 = wr[3];
    uint4 wa4 = wr[4], wa5 = wr[5], wa6 = wr[6], wa7 = wr[7];

    const unsigned short* xpr = (const unsigned short*)xp2;
    unsigned* wbA = hbufA[wave];
    unsigned* wbB = hbufB[wave];
    unsigned* wdst = ((lane >> 4) & 1) ? wbB : wbA;
    int hj = (lane >> 4) >> 1;       // 0 or 1
    float c = 0.0f;
    int dead = 0;                    // sticky anti-hang

// issue one 4-load poll round into dst[0..3] (no wait here; the wait is
// emitted -- counted -- where dst is READ)
#define PISSUE(dst, srcp)                                                   \
    _Pragma("unroll")                                                       \
    for (int i_ = 0; i_ < 4; ++i_)                                          \
        dst[i_] = __hip_atomic_load((srcp) + i_ * 64, __ATOMIC_RELAXED,     \
                                    __HIP_MEMORY_SCOPE_AGENT)
#define PCHK(buf, okv)                                                      \
    { int k_ = 1;                                                           \
      _Pragma("unroll")                                                     \
      for (int i_ = 0; i_ < 4; ++i_) k_ &= (buf[i_] != SENT);               \
      okv = __all(k_); }

    for (int t = 0; t < 4096; ++t) {
        unsigned short xraw = xpr[(size_t)t * 2048 + grow];

        if (t == 0) {
#pragma unroll
            for (int i = 0; i < 4; ++i)
                wdst[(hj + 2 * i) * 20 + (lane & 15)] = 0u;
        } else {
            const unsigned* src = hview + (size_t)(t - 1) * 256 + lane;
            unsigned va[4], vb[4], vc[4], v[4];
            unsigned spins = 0;
            // prime 2 rounds, then rotate: issue newest, check oldest.
            // Compiler emits counted vmcnt for the checked buffer ->
            // round period ~ latency/3 instead of full latency.
            PISSUE(va, src);
            PISSUE(vb, src);
            for (;;) {
                int ok;
                PISSUE(vc, src);
                PCHK(va, ok);
                if (ok) { v[0]=va[0]; v[1]=va[1]; v[2]=va[2]; v[3]=va[3]; break; }
                if (++spins > (1u << 20)) { dead = 1;
                    v[0]=va[0]; v[1]=va[1]; v[2]=va[2]; v[3]=va[3]; break; }
                PISSUE(va, src);
                PCHK(vb, ok);
                if (ok) { v[0]=vb[0]; v[1]=vb[1]; v[2]=vb[2]; v[3]=vb[3]; break; }
                PISSUE(vb, src);
                PCHK(vc, ok);
                if (ok) { v[0]=vc[0]; v[1]=vc[1]; v[2]=vc[2]; v[3]=vc[3]; break; }
            }
            if (dead) {
#pragma unroll
                for (int i = 0; i < 4; ++i)
                    if (v[i] == SENT) v[i] = 0x3C003C00u;   // f16 1.0 pair
            }
#pragma unroll
            for (int i = 0; i < 4; ++i)
                wdst[(hj + 2 * i) * 20 + (lane & 15)] = v[i];
        }

        // dot: h[kk*64 .. +63] . w -- A[kk] = chunk 2kk, B[kk] = chunk 2kk+1
        const uint4* q0 = (const uint4*)(wbA + kk * 20);
        const uint4* q1 = (const uint4*)(wbB + kk * 20);
        float a0 = 0.0f, a1 = 0.0f, a2 = 0.0f, a3 = 0.0f;
        uint4 h4;
        h4 = q0[0]; a0 = dot2h(wa0.x, h4.x, a0); a1 = dot2h(wa0.y, h4.y, a1);
                    a2 = dot2h(wa0.z, h4.z, a2); a3 = dot2h(wa0.w, h4.w, a3);
        h4 = q0[1]; a0 = dot2h(wa1.x, h4.x, a0); a1 = dot2h(wa1.y, h4.y, a1);
                    a2 = dot2h(wa1.z, h4.z, a2); a3 = dot2h(wa1.w, h4.w, a3);
        h4 = q0[2]; a0 = dot2h(wa2.x, h4.x, a0); a1 = dot2h(wa2.y, h4.y, a1);
                    a2 = dot2h(wa2.z, h4.z, a2); a3 = dot2h(wa2.w, h4.w, a3);
        h4 = q0[3]; a0 = dot2h(wa3.x, h4.x, a0); a1 = dot2h(wa3.y, h4.y, a1);
                    a2 = dot2h(wa3.z, h4.z, a2); a3 = dot2h(wa3.w, h4.w, a3);
        h4 = q1[0]; a0 = dot2h(wa4.x, h4.x, a0); a1 = dot2h(wa4.y, h4.y, a1);
                    a2 = dot2h(wa4.z, h4.z, a2); a3 = dot2h(wa4.w, h4.w, a3);
        h4 = q1[1]; a0 = dot2h(wa5.x, h4.x, a0); a1 = dot2h(wa5.y, h4.y, a1);
                    a2 = dot2h(wa5.z, h4.z, a2); a3 = dot2h(wa5.w, h4.w, a3);
        h4 = q1[2]; a0 = dot2h(wa6.x, h4.x, a0); a1 = dot2h(wa6.y, h4.y, a1);
                    a2 = dot2h(wa6.z, h4.z, a2); a3 = dot2h(wa6.w, h4.w, a3);
        h4 = q1[3]; a0 = dot2h(wa7.x, h4.x, a0); a1 = dot2h(wa7.y, h4.y, a1);
                    a2 = dot2h(wa7.z, h4.z, a2); a3 = dot2h(wa7.w, h4.w, a3);
        float acc = (a0 + a1) + (a2 + a3);
        acc += __shfl_xor(acc, 1);
        acc += __shfl_xor(acc, 2);
        acc += __shfl_xor(acc, 4);
        float gvt = acc + __bfloat162float(*(const __hip_bfloat16*)&xraw);

        float iv = __shfl(gvt, sp * 32 + 0);
        float fv = __shfl(gvt, sp * 32 + 8);
        float gg = __shfl(gvt, sp * 32 + 16);
        float ov = __shfl(gvt, sp * 32 + 24);
        // gate math predicated to the 2 lanes whose c,h are consumed:
        // 5 exp + 5 rcp are quarter-rate -- running them on 64 lanes
        // redundantly was pure critical-path issue cost.
        if ((lane & 31) == 0) {
            c = sigf(fv) * c + sigf(iv) * tanh_f(gg);
            float h = sigf(ov) * tanh_f(c);
            hout[t & 1][wave * 2 + sp] = h;
        }
        __syncthreads();                 // hout complete

        if (wave == 0 && lane < 16) {
            // pack 2 h -> f16x2 dword; ONE 64B-line store for the whole WG
            unsigned u0 = f2h_bits(hout[t & 1][2 * lane]);
            unsigned u1 = f2h_bits(hout[t & 1][2 * lane + 1]);
            __hip_atomic_store(hview + (size_t)t * 256 + wg * 16 + lane,
                               u0 | (u1 << 16),
                               __ATOMIC_RELAXED, __HIP_MEMORY_SCOPE_AGENT);
        }
        // no trailing barrier: hout[t&1] is next written at t+2 (other buffer
        // at t+1); reaching t+2 implies all waves passed the t+1 barrier.
    }
#undef PISSUE
#undef PCHK
}

// ---- K6: logits + log_softmax (h_hist is f16) ----------------------------
__global__ void __launch_bounds__(64) out_kernel(
    const unsigned short* __restrict__ hh16, const float* __restrict__ W1T,
    const void* __restrict__ b1raw, void* __restrict__ out,
    const int* __restrict__ flagp)
{
    __shared__ float hb[512];
    int flag = flagp[0];
    int t = blockIdx.x, j = threadIdx.x;
    const unsigned* src = (const unsigned*)(hh16 + (size_t)t * 512);
#pragma unroll
    for (int kq = 0; kq < 4; ++kq) {
        unsigned u = src[j * 4 + kq];
        hb[j * 8 + 2 * kq]     = h2f_lo(u);
        hb[j * 8 + 2 * kq + 1] = h2f_hi(u);
    }
    __syncthreads();

    float acc = flag ? __bfloat162float(((const __hip_bfloat16*)b1raw)[j])
                     : ((const float*)b1raw)[j];
#pragma unroll 8
    for (int k = 0; k < 512; ++k)
        acc += hb[k] * W1T[k * 64 + j];

    float m = acc;
#pragma unroll
    for (int o = 32; o; o >>= 1) m = fmaxf(m, __shfl_xor(m, o));
    float e = __expf(acc - m);
    float s = e;
#pragma unroll
    for (int o = 32; o; o >>= 1) s += __shfl_xor(s, o);
    float r = acc - m - __logf(s);
    if (flag) ((__hip_bfloat16*)out)[t * 64 + j] = __float2bfloat16(r);
    else      ((float*)out)[t * 64 + j] = r;
}

extern "C" void kernel_launch(void* const* d_in, const int* in_sizes, int n_in,
                              void* d_out, int out_size, void* d_ws, size_t ws_size,
                              hipStream_t stream)
{
    (void)in_sizes; (void)n_in; (void)out_size; (void)ws_size;
    const void* char_emb = d_in[0];
    const void* char_Wih = d_in[1];
    const void* char_Whh = d_in[2];
    const void* char_bih = d_in[3];
    const void* char_bhh = d_in[4];
    const void* word_emb = d_in[5];
    const void* Wih      = d_in[6];
    const void* Whh      = d_in[7];
    const void* bih      = d_in[8];
    const void* bhh      = d_in[9];
    const void* W1       = d_in[10];
    const void* b1       = d_in[11];
    const int* x     = (const int*)d_in[12];
    const int* chars = (const int*)d_in[13];
    const int* lens  = (const int*)d_in[14];

    float* ws    = (float*)d_ws;
    int*   flagp = (int*)(ws + OFF_FLAG);
    float* cembf = ws + OFF_CEMB;
    float* cWihf = ws + OFF_CWIH;
    float* cbihf = ws + OFF_CBIH;
    float* cbhhf = ws + OFF_CBHH;
    float* cWhhf = ws + OFF_CWHH;
    float* bihf  = ws + OFF_BIH;
    float* bhhf  = ws + OFF_BHH;
    float* W1T   = ws + OFF_W1T;
    float* cge   = ws + OFF_CGE;
    float* charh = ws + OFF_CH;
    __hip_bfloat16* xp2 = (__hip_bfloat16*)(ws + OFF_XP2);
    unsigned short* hh16 = (unsigned short*)(ws + OFF_HH);
    unsigned short* whh16 = (unsigned short*)(ws + OFF_WHH16);

    (void)hipMemsetAsync(hh16, 0xFF, (size_t)4096 * 512 * 2, stream);

    detect_kernel<<<1, 64, 0, stream>>>((const unsigned*)char_emb, flagp);

    convf_kernel<<<(8192 + 255) / 256, 256, 0, stream>>>(char_emb, cembf, 8192, flagp);
    convf_kernel<<<(32768 + 255) / 256, 256, 0, stream>>>(char_Wih, cWihf, 32768, flagp);
    convf_kernel<<<2, 256, 0, stream>>>(char_bih, cbihf, 512, flagp);
    convf_kernel<<<2, 256, 0, stream>>>(char_bhh, cbhhf, 512, flagp);
    convf_kernel<<<(65536 + 255) / 256, 256, 0, stream>>>(char_Whh, cWhhf, 65536, flagp);
    convf_kernel<<<8, 256, 0, stream>>>(bih, bihf, 2048, flagp);
    convf_kernel<<<8, 256, 0, stream>>>(bhh, bhhf, 2048, flagp);
    w1t_kernel<<<128, 256, 0, stream>>>(W1, W1T, flagp);
    whh16_kernel<<<4096, 256, 0, stream>>>(Whh, whh16, flagp);

    cge_kernel<<<128, 256, 0, stream>>>(cembf, cWihf, cbihf, cbhhf, cge);
    char_lstm_kernel<<<256, 256, 0, stream>>>(cge, cWhhf, chars, lens, charh);
    xp2_kernel<<<256, 256, 0, stream>>>(word_emb, x, charh, Wih, bihf, bhhf, xp2, flagp);
    word_lstm_kernel<<<16, 1024, 0, stream>>>(xp2, (const unsigned*)whh16, (unsigned*)hh16);
    out_kernel<<<4096, 64, 0, stream>>>(hh16, W1T, b1, d_out, flagp);
}

// Round 10
// 13266.905 us; speedup vs baseline: 1.0355x; 1.0355x over previous
//
#include <hip/hip_runtime.h>
#include <hip/hip_bf16.h>
#include <hip/hip_fp16.h>

// ---------------------------------------------------------------------------
// LSTMTagger: char-LSTM (4096x16, H=128) -> word-LSTM (serial 4096, H=512)
//             -> linear(64) + log_softmax.
// Wire dtype of float tensors detected at runtime (bf16 vs f32); kernels
// dual-path on device flag ws[0]: 1 = bf16, 0 = f32.
//
// Word LSTM (round 12): R8 kernel + fan-in 16 -> 8 WGs (the ONLY lever that
// has ever moved the 2.26-2.28us step: R0->R1 fan-in 32->16 gave -0.2us;
// everything else -- payload f32->f16, 2-4x compute cuts, weight pinning,
// bank "fixes", pipelined polls (R9: +0.26us, congestion), predicated
// transcendentals (R9: null, exec-masked ops issue at same rate) -- was
// null or negative).
//   8 WGs x 16 waves; WG owns 64 slots (2 cache lines); wave owns 4 slots;
//   lane (sp,g,kk)=sp*16+g*4+kk covers a 128-wide K-chunk: 16 uint4 weights,
//   16 LDS b128 reads + 64 dot2 (compute doubles -- hidden under spin, per
//   R8's invariance evidence). Poll: 4 loads/lane, only 7 REMOTE lines in
//   the max-over-N detect statistic (was 15); 128 polling waves (was 256).
//   Store: wave0 lanes<32, one instruction per 64B line, single writer.
//   Protocol otherwise unchanged: f16 line payload, 0xFFFFFFFF sentinel,
//   hout[2] double buffer, one barrier per step.
// Pre-commit: <3% move => declare agent-scope latency roofline (4096 serial
// cross-CU broadcasts x ~2.2us; sc0/XCD-local channel proven unsafe in R2).
// ---------------------------------------------------------------------------

#define OFF_FLAG  0
#define OFF_CEMB  16
#define OFF_CWIH  8208
#define OFF_CBIH  40976
#define OFF_CBHH  41488
#define OFF_CWHH  42000
#define OFF_BIH   107536
#define OFF_BHH   109584
#define OFF_W1T   111632
#define OFF_CGE   144400
#define OFF_CH    209936
#define OFF_XP2   734224
#define OFF_HH    4928528
#define OFF_WHH16 5977104   /* word Whh as packed f16: 1048576 ushort = 2MB */

#define SENT 0xFFFFFFFFu

#ifndef __has_builtin
#define __has_builtin(x) 0
#endif
#if __has_builtin(__builtin_amdgcn_fdot2)
#define HASDOT2 1
#endif

typedef _Float16 v2h __attribute__((ext_vector_type(2)));

__device__ __forceinline__ float sigf(float x) { return 1.0f / (1.0f + __expf(-x)); }
__device__ __forceinline__ float tanh_f(float x) { return 2.0f * sigf(2.0f * x) - 1.0f; }
__device__ __forceinline__ float b2f_lo(unsigned u) { return __uint_as_float(u << 16); }
__device__ __forceinline__ float b2f_hi(unsigned u) { return __uint_as_float(u & 0xFFFF0000u); }
// f16 bits -> f32 via _Float16 (no header intrinsics needed)
__device__ __forceinline__ float h2f_lo(unsigned u) {
    union { unsigned short s; _Float16 h; } c;
    c.s = (unsigned short)(u & 0xFFFFu);
    return (float)c.h;
}
__device__ __forceinline__ float h2f_hi(unsigned u) {
    union { unsigned short s; _Float16 h; } c;
    c.s = (unsigned short)(u >> 16);
    return (float)c.h;
}
// f32 -> f16 bits (RNE via compiler _Float16 conversion)
__device__ __forceinline__ unsigned short f2h_bits(float f) {
    union { unsigned short s; _Float16 h; } c;
    c.h = (_Float16)f;
    return c.s;
}
// packed-f16 2-way dot: acc += w.lo*h.lo + w.hi*h.hi
__device__ __forceinline__ float dot2h(unsigned w, unsigned h, float acc) {
#ifdef HASDOT2
    union U { unsigned u; v2h v; };
    U uw; uw.u = w;
    U uh; uh.u = h;
    return __builtin_amdgcn_fdot2(uw.v, uh.v, acc, false);
#else
    return acc + h2f_lo(w) * h2f_lo(h) + h2f_hi(w) * h2f_hi(h);
#endif
}

// ---- D0: dtype detect. ---------------------------------------------------
__global__ void detect_kernel(const unsigned* __restrict__ w, int* __restrict__ flagp) {
    unsigned v = w[threadIdx.x];
    unsigned e = (v >> 7) & 0xFF;
    int inr = (e >= 100 && e <= 140) ? 1 : 0;
    unsigned long long m = __ballot(inr);
    if (threadIdx.x == 0) flagp[0] = (__popcll(m) >= 56) ? 1 : 0;
}

// ---- K0: (bf16|f32) -> f32 convert ---------------------------------------
__global__ void convf_kernel(const void* __restrict__ s, float* __restrict__ d,
                             int n, const int* __restrict__ flagp) {
    int i = blockIdx.x * 256 + threadIdx.x;
    if (i >= n) return;
    d[i] = flagp[0] ? __bfloat162float(((const __hip_bfloat16*)s)[i])
                    : ((const float*)s)[i];
}

// ---- K0b: W1 (64x512) -> W1T (512x64) f32 --------------------------------
__global__ void w1t_kernel(const void* __restrict__ W1, float* __restrict__ W1T,
                           const int* __restrict__ flagp) {
    int i = blockIdx.x * 256 + threadIdx.x;   // 0..32767
    int j = i & 63, k = i >> 6;
    W1T[i] = flagp[0] ? __bfloat162float(((const __hip_bfloat16*)W1)[j * 512 + k])
                      : ((const float*)W1)[j * 512 + k];
}

// ---- K0c: word Whh -> packed f16 -----------------------------------------
__global__ void whh16_kernel(const void* __restrict__ src, unsigned short* __restrict__ dst,
                             const int* __restrict__ flagp) {
    int i = blockIdx.x * 256 + threadIdx.x;   // 0..1048575
    float f = flagp[0] ? __bfloat162float(((const __hip_bfloat16*)src)[i])
                       : ((const float*)src)[i];
    dst[i] = f2h_bits(f);
}

// ---- K1: char gate table ------------------------------------------------
__global__ void __launch_bounds__(256) cge_kernel(
    const float* __restrict__ cemb, const float* __restrict__ cWih,
    const float* __restrict__ cbih, const float* __restrict__ cbhh,
    float* __restrict__ cge)
{
    __shared__ float xe[64];
    int c = blockIdx.x, tid = threadIdx.x;
    if (tid < 64) xe[tid] = cemb[c * 64 + tid];
    __syncthreads();
#pragma unroll
    for (int rep = 0; rep < 2; ++rep) {
        int j = rep * 256 + tid;
        float acc = cbih[j] + cbhh[j];
#pragma unroll 8
        for (int k = 0; k < 64; ++k)
            acc += xe[k] * cWih[j * 64 + k];
        cge[c * 512 + j] = acc;
    }
}

// ---- K2: char LSTM -------------------------------------------------------
__global__ void __launch_bounds__(256) char_lstm_kernel(
    const float* __restrict__ cge, const float* __restrict__ Whh,
    const int* __restrict__ chars, const int* __restrict__ lens,
    float* __restrict__ char_h)
{
    __shared__ float hls[16][128];
    int tid = threadIdx.x;
    int wl = tid >> 4, sl = tid & 15;
    int w = blockIdx.x * 16 + wl;
    int len = lens[w];
    const int* cw = chars + w * 16;
    float c[8];
#pragma unroll
    for (int q = 0; q < 8; ++q) { c[q] = 0.0f; hls[wl][sl * 8 + q] = 0.0f; }

    for (int t = 0; t < 16; ++t) {
        __syncthreads();
        int ch = cw[t];
        const float* xg = cge + ch * 512;
        float acc[4][8];
#pragma unroll
        for (int g = 0; g < 4; ++g)
#pragma unroll
            for (int q = 0; q < 8; ++q)
                acc[g][q] = xg[g * 128 + sl * 8 + q];

        const float4* h4 = (const float4*)hls[wl];
#pragma unroll
        for (int g = 0; g < 4; ++g) {
            const float4* wbase = ((const float4*)Whh) + (g * 128 + sl * 8) * 32;
            for (int k4 = 0; k4 < 32; ++k4) {
                float4 hv = h4[k4];
#pragma unroll
                for (int q = 0; q < 8; ++q) {
                    float4 wv = wbase[q * 32 + k4];
                    acc[g][q] += wv.x * hv.x + wv.y * hv.y + wv.z * hv.z + wv.w * hv.w;
                }
            }
        }
        __syncthreads();
        if (t < len) {
#pragma unroll
            for (int q = 0; q < 8; ++q) {
                float iv = sigf(acc[0][q]);
                float fv = sigf(acc[1][q]);
                float gv = tanh_f(acc[2][q]);
                float ov = sigf(acc[3][q]);
                c[q] = fv * c[q] + iv * gv;
                hls[wl][sl * 8 + q] = ov * tanh_f(c[q]);
            }
        }
    }
    __syncthreads();
#pragma unroll
    for (int q = 0; q < 8; ++q)
        char_h[w * 128 + sl * 8 + q] = hls[wl][sl * 8 + q];
}

// ---- K3: word x-part gates (bf16 out) ------------------------------------
__global__ void __launch_bounds__(256) xp2_kernel(
    const void* __restrict__ wemb, const int* __restrict__ x,
    const float* __restrict__ char_h, const void* __restrict__ Wraw,
    const float* __restrict__ bih, const float* __restrict__ bhh,
    __hip_bfloat16* __restrict__ xp2, const int* __restrict__ flagp)
{
    __shared__ float feat[16][384];
    int flag = flagp[0];
    int tid = threadIdx.x, tl = tid >> 4, sl = tid & 15;
    int t = blockIdx.x * 16 + tl;
    int xw = x[t];
    for (int idx = sl; idx < 384; idx += 16) {
        float v;
        if (idx < 256)
            v = flag ? __bfloat162float(((const __hip_bfloat16*)wemb)[(size_t)xw * 256 + idx])
                     : ((const float*)wemb)[(size_t)xw * 256 + idx];
        else
            v = char_h[t * 128 + (idx - 256)];
        feat[tl][idx] = v;
    }
    __syncthreads();

    const float4* f4 = (const float4*)feat[tl];
    for (int rb = 0; rb < 4; ++rb) {
        int r0 = rb * 512 + sl * 32;
        for (int qc = 0; qc < 4; ++qc) {
            int rr = r0 + qc * 8;
            float acc[8];
#pragma unroll
            for (int q = 0; q < 8; ++q)
                acc[q] = bih[rr + q] + bhh[rr + q];
            if (!flag) {
                const float4* wb = ((const float4*)Wraw) + (size_t)rr * 96;
                for (int k4 = 0; k4 < 96; ++k4) {
                    float4 fv = f4[k4];
#pragma unroll
                    for (int q = 0; q < 8; ++q) {
                        float4 wv = wb[q * 96 + k4];
                        acc[q] += wv.x * fv.x + wv.y * fv.y + wv.z * fv.z + wv.w * fv.w;
                    }
                }
            } else {
                const uint2* wb = ((const uint2*)Wraw) + (size_t)rr * 96;
                for (int k4 = 0; k4 < 96; ++k4) {
                    float4 fv = f4[k4];
#pragma unroll
                    for (int q = 0; q < 8; ++q) {
                        uint2 wv = wb[q * 96 + k4];
                        acc[q] += b2f_lo(wv.x) * fv.x + b2f_hi(wv.x) * fv.y
                                + b2f_lo(wv.y) * fv.z + b2f_hi(wv.y) * fv.w;
                    }
                }
            }
#pragma unroll
            for (int q = 0; q < 8; ++q)
                xp2[(size_t)t * 2048 + rr + q] = __float2bfloat16(acc[q]);
        }
    }
}

// ---- K5: serial word LSTM (8 WGs, f16 payload, dot2 inner) ---------------
__global__ void __launch_bounds__(1024, 1) word_lstm_kernel(
    const __hip_bfloat16* __restrict__ xp2, const unsigned* __restrict__ whh16,
    unsigned* __restrict__ hview)
{
    // staging split A (even chunks) / B (odd chunks), 8 chunks x 20 dwords
    // per wave; 16-lane groups with equal kk read IDENTICAL addresses
    // (broadcast, free); the 4 kk groups hit distinct banks.
    __shared__ __align__(16) unsigned hbufA[16][160];
    __shared__ __align__(16) unsigned hbufB[16][160];
    __shared__ float hout[2][64];    // double-buffered fresh h (f32)
    int wg = blockIdx.x;
    int tid = threadIdx.x;
    int wave = tid >> 6, lane = tid & 63;
    int sp = lane >> 4;              // sub-slot 0..3 within the wave
    int g  = (lane >> 2) & 3;        // gate i/f/g/o
    int kk = lane & 3;               // K-chunk (128 h-values wide)
    int slot = wg * 64 + wave * 4 + sp;
    int grow = g * 512 + slot;

    // weights: Whh[grow][kk*128 .. +127] as 64 packed-f16 dwords = 16 uint4
    const uint4* wr = (const uint4*)(whh16 + (size_t)grow * 256) + kk * 16;
    uint4 wa0  = wr[0],  wa1  = wr[1],  wa2  = wr[2],  wa3  = wr[3];
    uint4 wa4  = wr[4],  wa5  = wr[5],  wa6  = wr[6],  wa7  = wr[7];
    uint4 wa8  = wr[8],  wa9  = wr[9],  wa10 = wr[10], wa11 = wr[11];
    uint4 wa12 = wr[12], wa13 = wr[13], wa14 = wr[14], wa15 = wr[15];

    const unsigned short* xpr = (const unsigned short*)xp2;
    unsigned* wbA = hbufA[wave];
    unsigned* wbB = hbufB[wave];
    unsigned* wdst = ((lane >> 4) & 1) ? wbB : wbA;
    int hj = (lane >> 4) >> 1;       // 0 or 1
    float c = 0.0f;
    int dead = 0;                    // sticky anti-hang

    for (int t = 0; t < 4096; ++t) {
        // h-independent: issue before the poll so latency hides under the spin
        unsigned short xraw = xpr[(size_t)t * 2048 + grow];

        if (t == 0) {
            // h_{-1} = 0 (f16 zero pair = 0x00000000)
#pragma unroll
            for (int i = 0; i < 4; ++i)
                wdst[(hj + 2 * i) * 20 + (lane & 15)] = 0u;
        } else {
            // poll h_{t-1}: lane l covers dwords l+64i (coalesced 256B/instr)
            const unsigned* src = hview + (size_t)(t - 1) * 256 + lane;
            unsigned v[4];
            unsigned spins = 0;
            for (;;) {
#pragma unroll
                for (int i = 0; i < 4; ++i)
                    v[i] = __hip_atomic_load(src + i * 64, __ATOMIC_RELAXED,
                                             __HIP_MEMORY_SCOPE_AGENT);
                int ok = 1;
#pragma unroll
                for (int i = 0; i < 4; ++i) ok &= (v[i] != SENT);
                if (dead || __all(ok)) break;
                if (++spins > (1u << 22)) { dead = 1; break; }
            }
            if (dead) {
#pragma unroll
                for (int i = 0; i < 4; ++i)
                    if (v[i] == SENT) v[i] = 0x3C003C00u;   // f16 1.0 pair
            }
            // stage raw dwords into split A/B layout
#pragma unroll
            for (int i = 0; i < 4; ++i)
                wdst[(hj + 2 * i) * 20 + (lane & 15)] = v[i];
        }

        // dot: h[kk*128 .. +127] . w -- chunks 4kk..4kk+3 = A[2kk], B[2kk],
        // A[2kk+1], B[2kk+1]; 16 b128 reads + 64 dot2, 4 acc chains
        float a0 = 0.0f, a1 = 0.0f, a2 = 0.0f, a3 = 0.0f;
        uint4 h4;
        const uint4* q;
        q = (const uint4*)(wbA + (2 * kk) * 20);
        h4 = q[0]; a0 = dot2h(wa0.x, h4.x, a0); a1 = dot2h(wa0.y, h4.y, a1);
                   a2 = dot2h(wa0.z, h4.z, a2); a3 = dot2h(wa0.w, h4.w, a3);
        h4 = q[1]; a0 = dot2h(wa1.x, h4.x, a0); a1 = dot2h(wa1.y, h4.y, a1);
                   a2 = dot2h(wa1.z, h4.z, a2); a3 = dot2h(wa1.w, h4.w, a3);
        h4 = q[2]; a0 = dot2h(wa2.x, h4.x, a0); a1 = dot2h(wa2.y, h4.y, a1);
                   a2 = dot2h(wa2.z, h4.z, a2); a3 = dot2h(wa2.w, h4.w, a3);
        h4 = q[3]; a0 = dot2h(wa3.x, h4.x, a0); a1 = dot2h(wa3.y, h4.y, a1);
                   a2 = dot2h(wa3.z, h4.z, a2); a3 = dot2h(wa3.w, h4.w, a3);
        q = (const uint4*)(wbB + (2 * kk) * 20);
        h4 = q[0]; a0 = dot2h(wa4.x, h4.x, a0); a1 = dot2h(wa4.y, h4.y, a1);
                   a2 = dot2h(wa4.z, h4.z, a2); a3 = dot2h(wa4.w, h4.w, a3);
        h4 = q[1]; a0 = dot2h(wa5.x, h4.x, a0); a1 = dot2h(wa5.y, h4.y, a1);
                   a2 = dot2h(wa5.z, h4.z, a2); a3 = dot2h(wa5.w, h4.w, a3);
        h4 = q[2]; a0 = dot2h(wa6.x, h4.x, a0); a1 = dot2h(wa6.y, h4.y, a1);
                   a2 = dot2h(wa6.z, h4.z, a2); a3 = dot2h(wa6.w, h4.w, a3);
        h4 = q[3]; a0 = dot2h(wa7.x, h4.x, a0); a1 = dot2h(wa7.y, h4.y, a1);
                   a2 = dot2h(wa7.z, h4.z, a2); a3 = dot2h(wa7.w, h4.w, a3);
        q = (const uint4*)(wbA + (2 * kk + 1) * 20);
        h4 = q[0]; a0 = dot2h(wa8.x, h4.x, a0); a1 = dot2h(wa8.y, h4.y, a1);
                   a2 = dot2h(wa8.z, h4.z, a2); a3 = dot2h(wa8.w, h4.w, a3);
        h4 = q[1]; a0 = dot2h(wa9.x, h4.x, a0); a1 = dot2h(wa9.y, h4.y, a1);
                   a2 = dot2h(wa9.z, h4.z, a2); a3 = dot2h(wa9.w, h4.w, a3);
        h4 = q[2]; a0 = dot2h(wa10.x, h4.x, a0); a1 = dot2h(wa10.y, h4.y, a1);
                   a2 = dot2h(wa10.z, h4.z, a2); a3 = dot2h(wa10.w, h4.w, a3);
        h4 = q[3]; a0 = dot2h(wa11.x, h4.x, a0); a1 = dot2h(wa11.y, h4.y, a1);
                   a2 = dot2h(wa11.z, h4.z, a2); a3 = dot2h(wa11.w, h4.w, a3);
        q = (const uint4*)(wbB + (2 * kk + 1) * 20);
        h4 = q[0]; a0 = dot2h(wa12.x, h4.x, a0); a1 = dot2h(wa12.y, h4.y, a1);
                   a2 = dot2h(wa12.z, h4.z, a2); a3 = dot2h(wa12.w, h4.w, a3);
        h4 = q[1]; a0 = dot2h(wa13.x, h4.x, a0); a1 = dot2h(wa13.y, h4.y, a1);
                   a2 = dot2h(wa13.z, h4.z, a2); a3 = dot2h(wa13.w, h4.w, a3);
        h4 = q[2]; a0 = dot2h(wa14.x, h4.x, a0); a1 = dot2h(wa14.y, h4.y, a1);
                   a2 = dot2h(wa14.z, h4.z, a2); a3 = dot2h(wa14.w, h4.w, a3);
        h4 = q[3]; a0 = dot2h(wa15.x, h4.x, a0); a1 = dot2h(wa15.y, h4.y, a1);
                   a2 = dot2h(wa15.z, h4.z, a2); a3 = dot2h(wa15.w, h4.w, a3);

        float acc = (a0 + a1) + (a2 + a3);
        acc += __shfl_xor(acc, 1);
        acc += __shfl_xor(acc, 2);
        float gvt = acc + __bfloat162float(*(const __hip_bfloat16*)&xraw);

        // gates for this lane's slot sp live at lanes sp*16 + {0,4,8,12}
        float iv = __shfl(gvt, sp * 16 + 0);
        float fv = __shfl(gvt, sp * 16 + 4);
        float gg = __shfl(gvt, sp * 16 + 8);
        float ov = __shfl(gvt, sp * 16 + 12);
        c = sigf(fv) * c + sigf(iv) * tanh_f(gg);
        float h = sigf(ov) * tanh_f(c);

        if ((lane & 15) == 0) hout[t & 1][wave * 4 + sp] = h;
        __syncthreads();                 // hout complete

        if (wave == 0 && lane < 32) {
            // pack 2 h -> f16x2 dword; WG's 64 slots = 32 dwords = 2 lines,
            // each 64B line written by ONE instruction (single writer)
            unsigned u0 = f2h_bits(hout[t & 1][2 * lane]);
            unsigned u1 = f2h_bits(hout[t & 1][2 * lane + 1]);
            __hip_atomic_store(hview + (size_t)t * 256 + wg * 32 + lane,
                               u0 | (u1 << 16),
                               __ATOMIC_RELAXED, __HIP_MEMORY_SCOPE_AGENT);
        }
        // no trailing barrier: hout[t&1] is next written at t+2 (other buffer
        // at t+1); reaching t+2 implies all waves passed the t+1 barrier.
    }
}

// ---- K6: logits + log_softmax (h_hist is f16) ----------------------------
__global__ void __launch_bounds__(64) out_kernel(
    const unsigned short* __restrict__ hh16, const float* __restrict__ W1T,
    const void* __restrict__ b1raw, void* __restrict__ out,
    const int* __restrict__ flagp)
{
    __shared__ float hb[512];
    int flag = flagp[0];
    int t = blockIdx.x, j = threadIdx.x;
    const unsigned* src = (const unsigned*)(hh16 + (size_t)t * 512);
#pragma unroll
    for (int kq = 0; kq < 4; ++kq) {
        unsigned u = src[j * 4 + kq];
        hb[j * 8 + 2 * kq]     = h2f_lo(u);
        hb[j * 8 + 2 * kq + 1] = h2f_hi(u);
    }
    __syncthreads();

    float acc = flag ? __bfloat162float(((const __hip_bfloat16*)b1raw)[j])
                     : ((const float*)b1raw)[j];
#pragma unroll 8
    for (int k = 0; k < 512; ++k)
        acc += hb[k] * W1T[k * 64 + j];

    float m = acc;
#pragma unroll
    for (int o = 32; o; o >>= 1) m = fmaxf(m, __shfl_xor(m, o));
    float e = __expf(acc - m);
    float s = e;
#pragma unroll
    for (int o = 32; o; o >>= 1) s += __shfl_xor(s, o);
    float r = acc - m - __logf(s);
    if (flag) ((__hip_bfloat16*)out)[t * 64 + j] = __float2bfloat16(r);
    else      ((float*)out)[t * 64 + j] = r;
}

extern "C" void kernel_launch(void* const* d_in, const int* in_sizes, int n_in,
                              void* d_out, int out_size, void* d_ws, size_t ws_size,
                              hipStream_t stream)
{
    (void)in_sizes; (void)n_in; (void)out_size; (void)ws_size;
    const void* char_emb = d_in[0];
    const void* char_Wih = d_in[1];
    const void* char_Whh = d_in[2];
    const void* char_bih = d_in[3];
    const void* char_bhh = d_in[4];
    const void* word_emb = d_in[5];
    const void* Wih      = d_in[6];
    const void* Whh      = d_in[7];
    const void* bih      = d_in[8];
    const void* bhh      = d_in[9];
    const void* W1       = d_in[10];
    const void* b1       = d_in[11];
    const int* x     = (const int*)d_in[12];
    const int* chars = (const int*)d_in[13];
    const int* lens  = (const int*)d_in[14];

    float* ws    = (float*)d_ws;
    int*   flagp = (int*)(ws + OFF_FLAG);
    float* cembf = ws + OFF_CEMB;
    float* cWihf = ws + OFF_CWIH;
    float* cbihf = ws + OFF_CBIH;
    float* cbhhf = ws + OFF_CBHH;
    float* cWhhf = ws + OFF_CWHH;
    float* bihf  = ws + OFF_BIH;
    float* bhhf  = ws + OFF_BHH;
    float* W1T   = ws + OFF_W1T;
    float* cge   = ws + OFF_CGE;
    float* charh = ws + OFF_CH;
    __hip_bfloat16* xp2 = (__hip_bfloat16*)(ws + OFF_XP2);
    unsigned short* hh16 = (unsigned short*)(ws + OFF_HH);
    unsigned short* whh16 = (unsigned short*)(ws + OFF_WHH16);

    (void)hipMemsetAsync(hh16, 0xFF, (size_t)4096 * 512 * 2, stream);

    detect_kernel<<<1, 64, 0, stream>>>((const unsigned*)char_emb, flagp);

    convf_kernel<<<(8192 + 255) / 256, 256, 0, stream>>>(char_emb, cembf, 8192, flagp);
    convf_kernel<<<(32768 + 255) / 256, 256, 0, stream>>>(char_Wih, cWihf, 32768, flagp);
    convf_kernel<<<2, 256, 0, stream>>>(char_bih, cbihf, 512, flagp);
    convf_kernel<<<2, 256, 0, stream>>>(char_bhh, cbhhf, 512, flagp);
    convf_kernel<<<(65536 + 255) / 256, 256, 0, stream>>>(char_Whh, cWhhf, 65536, flagp);
    convf_kernel<<<8, 256, 0, stream>>>(bih, bihf, 2048, flagp);
    convf_kernel<<<8, 256, 0, stream>>>(bhh, bhhf, 2048, flagp);
    w1t_kernel<<<128, 256, 0, stream>>>(W1, W1T, flagp);
    whh16_kernel<<<4096, 256, 0, stream>>>(Whh, whh16, flagp);

    cge_kernel<<<128, 256, 0, stream>>>(cembf, cWihf, cbihf, cbhhf, cge);
    char_lstm_kernel<<<256, 256, 0, stream>>>(cge, cWhhf, chars, lens, charh);
    xp2_kernel<<<256, 256, 0, stream>>>(word_emb, x, charh, Wih, bihf, bhhf, xp2, flagp);
    word_lstm_kernel<<<8, 1024, 0, stream>>>(xp2, (const unsigned*)whh16, (unsigned*)hh16);
    out_kernel<<<4096, 64, 0, stream>>>(hh16, W1T, b1, d_out, flagp);
}